// Round 15
// baseline (256.761 us; speedup 1.0000x reference)
//
#include <hip/hip_runtime.h>
#include <hip/hip_bf16.h>

#define NROWS 16384
#define DIM   1024
#define NT    8                          // K-tiles (1024 / 128 i8)
#define NTILE 128                        // 128-row tiles per dim
#define NBLK  (NTILE * (NTILE + 1) / 2)  // 8256 upper-tri blocks (= 8*1032)
#define SW    16                         // strip width (16 B-panels = 2MB, L2-fit)

typedef int i32x4 __attribute__((ext_vector_type(4)));

// monotone float -> uint key (order-preserving), so atomicMax works on floats
__device__ __forceinline__ unsigned fkey(float f) {
    unsigned u = __float_as_uint(f);
    return (u & 0x80000000u) ? ~u : (u | 0x80000000u);
}
__device__ __forceinline__ float funkey(unsigned k) {
    unsigned u = (k & 0x80000000u) ? (k & 0x7fffffffu) : ~k;
    return __uint_as_float(u);
}

// One block per row: fp32 norm, quantize q = round(127*x/||x||) (i8), store
// packed; also per-row inverse quantized norm s = 1/||q|| so sim is the EXACT
// cosine of the integer vectors (removes norm quantization error).
__global__ void normalize_rows(const float* __restrict__ x,
                               signed char* __restrict__ xq,
                               float* __restrict__ sinv,
                               unsigned* __restrict__ rowmax) {
    const int row = blockIdx.x;
    const int t = threadIdx.x;                      // 256 threads, 1 float4 each
    const float4 v = ((const float4*)(x + (size_t)row * DIM))[t];
    float ss = v.x * v.x + v.y * v.y + v.z * v.z + v.w * v.w;
#pragma unroll
    for (int off = 32; off > 0; off >>= 1) ss += __shfl_xor(ss, off);
    __shared__ float wss[4];
    __shared__ int   wqs[4];
    if ((t & 63) == 0) wss[t >> 6] = ss;
    __syncthreads();
    const float tot = wss[0] + wss[1] + wss[2] + wss[3];
    const float scale = 127.0f / fmaxf(sqrtf(tot), 1e-12f);
    int qx = __float2int_rn(v.x * scale);
    int qy = __float2int_rn(v.y * scale);
    int qz = __float2int_rn(v.z * scale);
    int qw = __float2int_rn(v.w * scale);
    qx = max(-127, min(127, qx)); qy = max(-127, min(127, qy));
    qz = max(-127, min(127, qz)); qw = max(-127, min(127, qw));
    const int p = (qx & 0xff) | ((qy & 0xff) << 8) | ((qz & 0xff) << 16) | ((qw & 0xff) << 24);
    ((int*)(xq + (size_t)row * DIM))[t] = p;
    int qs = qx * qx + qy * qy + qz * qz + qw * qw;
#pragma unroll
    for (int off = 32; off > 0; off >>= 1) qs += __shfl_xor(qs, off);
    if ((t & 63) == 0) wqs[t >> 6] = qs;
    __syncthreads();
    if (t == 0) {
        const int qtot = max(wqs[0] + wqs[1] + wqs[2] + wqs[3], 1);
        sinv[row] = 1.0f / sqrtf((float)qtot);
        rowmax[row] = 0u;
    }
}

// ---- simmax: i8 128^2, strip-ordered, DOUBLE-BUFFERED (R4 interleave),
// LDS-merged epilogue atomics. Per tile: reads from cur buf, stages for t+1
// into the other buf mid-tile (drain lands ~900cy later, off critical path),
// one vmcnt(0)+raw-barrier per tile. Epilogue merges all per-wave maxes in
// shared memory, then issues ONE global atomic per row/col (256/block).

#define SB() __builtin_amdgcn_sched_barrier(0)

__global__ __launch_bounds__(256, 2)
void simmax_kernel(const signed char* __restrict__ xq,
                   const float* __restrict__ sinv,
                   unsigned* __restrict__ rowmax) {
    // bijective XCD-chunked swizzle (8256 = 8 * 1032)
    const int bid = blockIdx.x;
    int rem = (bid & 7) * (NBLK / 8) + (bid >> 3);
    // strip-order decode: strip s has 256*s + 136 tiles
    int s = 0;
    for (;;) {
        const int sz = 256 * s + 136;
        if (rem < sz) break;
        rem -= sz;
        ++s;
    }
    int it, jt;
    const int full = 256 * s;            // tiles with it < 16s (full width 16)
    if (rem < full) {
        it = rem >> 4;
        jt = SW * s + (rem & 15);
    } else {
        int r2 = rem - full;
        int d = 0;
        while (r2 >= SW - d) { r2 -= SW - d; ++d; }
        it = SW * s + d;
        jt = it + r2;
    }
    const bool diag = (jt == it);
    const int rowBase = it * 128;
    const int colBase = jt * 128;

    __shared__ __align__(16) char lds[2][2][128][128];  // [buf][A/B][row][128B] 64 KiB
    __shared__ unsigned redmax[256];                    // [0..127] rows, [128..255] cols

    const int t    = threadIdx.x;                    // 256 = 4 waves
    const int lane = t & 63;
    const int wid  = t >> 6;
    const int wr2  = wid >> 1;     // 0..1 (M)
    const int wc2  = wid & 1;      // 0..1 (N)
    const int l15  = lane & 15;
    const int hi   = lane >> 4;

    redmax[t] = 0u;

    // staging: chunk c = j*256 + t (j=0..7); op = c>>10 (A/B); cc = c&1023;
    // row = cc>>3, ch = cc&7. LDS dest LINEAR (c*16 B within buf); SOURCE
    // chunk pre-swizzled (ch ^ (row&7)) so swizzled ds_read finds it (#21).
    const signed char* srcp[8];
#pragma unroll
    for (int j = 0; j < 8; ++j) {
        const int c   = j * 256 + t;
        const int op  = c >> 10;
        const int cc  = c & 1023;
        const int row = cc >> 3;
        const int ch  = cc & 7;
        const int gr  = (op ? colBase : rowBase) + row;
        srcp[j] = xq + (size_t)gr * DIM + (ch ^ (row & 7)) * 16;
    }

    // prologue: stage tile 0 into buf 0, drain once
#pragma unroll
    for (int j = 0; j < 8; ++j) {
        __builtin_amdgcn_global_load_lds(
            (const __attribute__((address_space(1))) void*)srcp[j],
            (__attribute__((address_space(3))) void*)(&lds[0][0][0][0] + (j * 256 + wid * 64) * 16),
            16, 0, 0);
        srcp[j] += 128;
    }
    asm volatile("s_waitcnt vmcnt(0)" ::: "memory");
    __builtin_amdgcn_s_barrier();
    SB();

    i32x4 acc[4][4];
#pragma unroll
    for (int m = 0; m < 4; ++m)
#pragma unroll
        for (int n = 0; n < 4; ++n)
            acc[m][n] = (i32x4){0, 0, 0, 0};

    for (int tk = 0; tk < NT; ++tk) {
        char* curb = &lds[tk & 1][0][0][0];
        char* nxtb = &lds[(tk & 1) ^ 1][0][0][0];
        const bool pf = (tk + 1 < NT);

        i32x4 af[4][2], bf[4][2];
        // A reads (8 ds_read_b128)
#pragma unroll
        for (int m = 0; m < 4; ++m)
#pragma unroll
            for (int kk = 0; kk < 2; ++kk) {
                const int row = wr2 * 64 + m * 16 + l15;
                const int chn = (kk * 4 + hi) ^ (row & 7);
                af[m][kk] = *(const i32x4*)(curb + row * 128 + chn * 16);
            }
        // stage A' for t+1 into the other buffer (free since last barrier)
        if (pf) {
#pragma unroll
            for (int j = 0; j < 4; ++j) {
                __builtin_amdgcn_global_load_lds(
                    (const __attribute__((address_space(1))) void*)srcp[j],
                    (__attribute__((address_space(3))) void*)(nxtb + (j * 256 + wid * 64) * 16),
                    16, 0, 0);
                srcp[j] += 128;
            }
        }
        // B reads (8 ds_read_b128)
#pragma unroll
        for (int n = 0; n < 4; ++n)
#pragma unroll
            for (int kk = 0; kk < 2; ++kk) {
                const int row = wc2 * 64 + n * 16 + l15;
                const int chn = (kk * 4 + hi) ^ (row & 7);
                bf[n][kk] = *(const i32x4*)(curb + 16384 + row * 128 + chn * 16);
            }
        if (pf) {
#pragma unroll
            for (int j = 4; j < 8; ++j) {
                __builtin_amdgcn_global_load_lds(
                    (const __attribute__((address_space(1))) void*)srcp[j],
                    (__attribute__((address_space(3))) void*)(nxtb + (j * 256 + wid * 64) * 16),
                    16, 0, 0);
                srcp[j] += 128;
            }
        }
        // MFMA cluster
        __builtin_amdgcn_s_setprio(1);
#pragma unroll
        for (int m = 0; m < 4; ++m)
#pragma unroll
            for (int n = 0; n < 4; ++n)
#pragma unroll
                for (int kk = 0; kk < 2; ++kk)
                    acc[m][n] = __builtin_amdgcn_mfma_i32_16x16x64_i8(
                        af[m][kk], bf[n][kk], acc[m][n], 0, 0, 0);
        __builtin_amdgcn_s_setprio(0);

        // one barrier per tile: stages (issued mid-tile, ~900cy old) drained,
        // next buffer published; parity flips.
        asm volatile("s_waitcnt vmcnt(0)" ::: "memory");
        __builtin_amdgcn_s_barrier();
        SB();
    }

    // ---- epilogue: scaled tile max -> LDS merge -> 1 global atomic/row|col ----
    // C/D layout: col = lane&15, row = (lane>>4)*4 + reg  [m89/m91, dtype-indep]
    const int g  = lane >> 4;
    const int cl = lane & 15;

    float scl_col[4];
#pragma unroll
    for (int n = 0; n < 4; ++n)
        scl_col[n] = sinv[colBase + wc2 * 64 + n * 16 + cl];
    float srow[4][4];
#pragma unroll
    for (int m = 0; m < 4; ++m)
#pragma unroll
        for (int r = 0; r < 4; ++r)
            srow[m][r] = sinv[rowBase + wr2 * 64 + m * 16 + g * 4 + r];

    // row-direction: max_j (s_j * d_ij) into redmax[0..127]
#pragma unroll
    for (int m = 0; m < 4; ++m)
#pragma unroll
        for (int r = 0; r < 4; ++r) {
            const int grow = wr2 * 64 + m * 16 + g * 4 + r;
            float v = -1e30f;
#pragma unroll
            for (int n = 0; n < 4; ++n) {
                const int gcol = wc2 * 64 + n * 16 + cl;
                float f = (float)acc[m][n][r] * scl_col[n];
                if (diag && grow == gcol) f = -1e30f;   // exclude self-sim
                v = fmaxf(v, f);
            }
            v = fmaxf(v, __shfl_xor(v, 1));
            v = fmaxf(v, __shfl_xor(v, 2));
            v = fmaxf(v, __shfl_xor(v, 4));
            v = fmaxf(v, __shfl_xor(v, 8));
            if (cl == 0) atomicMax(&redmax[grow], fkey(v));
        }

    // col-direction (transpose): max_i (s_i * d_ij) into redmax[128..255]
    if (!diag) {
#pragma unroll
        for (int n = 0; n < 4; ++n) {
            float v = -1e30f;
#pragma unroll
            for (int m = 0; m < 4; ++m)
#pragma unroll
                for (int r = 0; r < 4; ++r)
                    v = fmaxf(v, (float)acc[m][n][r] * srow[m][r]);
            v = fmaxf(v, __shfl_xor(v, 16));
            v = fmaxf(v, __shfl_xor(v, 32));
            if (g == 0) atomicMax(&redmax[128 + wc2 * 64 + n * 16 + cl], fkey(v));
        }
    }
    __syncthreads();

    const unsigned k = redmax[t];
    if (t < 128) {
        atomicMax(rowmax + rowBase + t, k);
    } else if (!diag) {
        atomicMax(rowmax + colBase + (t - 128), k);
    }
}

__global__ void finalize_kernel(const unsigned* __restrict__ rowmax,
                                const float* __restrict__ sinv,
                                float* __restrict__ out) {
    const int t = threadIdx.x;
    float s = 0.f;
    for (int r = t; r < NROWS; r += 256) {
        const float m = fminf(sinv[r] * funkey(rowmax[r]), 1.0f);   // cos, clamp
        s += logf(2.0f - 2.0f * m + 1e-8f);
    }
#pragma unroll
    for (int off = 32; off > 0; off >>= 1) s += __shfl_xor(s, off);
    __shared__ float ws[4];
    if ((t & 63) == 0) ws[t >> 6] = s;
    __syncthreads();
    if (t == 0) out[0] = -0.5f * (ws[0] + ws[1] + ws[2] + ws[3]) / (float)NROWS;
}

extern "C" void kernel_launch(void* const* d_in, const int* in_sizes, int n_in,
                              void* d_out, int out_size, void* d_ws, size_t ws_size,
                              hipStream_t stream) {
    const float* x = (const float*)d_in[0];
    signed char* xq = (signed char*)d_ws;                                // 16 MB
    float* sinv = (float*)((char*)d_ws + (size_t)NROWS * DIM);           // 64 KB
    unsigned* rowmax = (unsigned*)((char*)d_ws + (size_t)NROWS * DIM + NROWS * sizeof(float));
    float* out = (float*)d_out;

    normalize_rows<<<NROWS, 256, 0, stream>>>(x, xq, sinv, rowmax);
    simmax_kernel<<<NBLK, 256, 0, stream>>>(xq, sinv, rowmax);
    finalize_kernel<<<1, 256, 0, stream>>>(rowmax, sinv, out);
}